// Round 3
// baseline (2115.793 us; speedup 1.0000x reference)
//
#include <hip/hip_runtime.h>

// ---------------- constants ----------------
#define S_LEN 2048
#define NB 4
#define NH 16
#define BHN 64          // NB*NH
#define DM 1024
#define DEP 64
#define MROWS 8192      // NB*S_LEN

typedef __attribute__((ext_vector_type(8))) short short8;
typedef __attribute__((ext_vector_type(4))) float f32x4;

#define MFMA_BF16(a, b, c) __builtin_amdgcn_mfma_f32_16x16x32_bf16((a), (b), (c), 0, 0, 0)

typedef __attribute__((address_space(1))) const void* as1cv;
typedef __attribute__((address_space(3))) void* as3v;

__device__ __forceinline__ void gld16(const void* g, void* l) {
  // async global->LDS, 16B per lane; LDS dest = wave-uniform base + lane*16
  __builtin_amdgcn_global_load_lds((as1cv)g, (as3v)l, 16, 0, 0);
}

__device__ __forceinline__ unsigned short f2bf(float f) {
  unsigned u = __float_as_uint(f);
  u += 0x7fffu + ((u >> 16) & 1u);   // round-to-nearest-even
  return (unsigned short)(u >> 16);
}

// packed fp32x2 -> bf16x2 (RNE), 1 instruction; S0 -> low16, S1 -> high16
__device__ __forceinline__ unsigned cvtpk(float a, float b) {
  unsigned r;
  asm("v_cvt_pk_bf16_f32 %0, %1, %2" : "=v"(r) : "v"(a), "v"(b));
  return r;
}

// swizzled short-index of logical (row, 8-short granule) in a [rows][64] bf16 tile
__device__ __forceinline__ int SWZ(int row, int gran) {
  return row * 64 + ((gran ^ (row & 7)) << 3);
}

// ---------------- gate: validity[b][h] = sigmoid(pf @ wg + bg) ----------------
__global__ void gate_kernel(const float* __restrict__ pf, const float* __restrict__ wg,
                            const float* __restrict__ bg, float* __restrict__ validity) {
  int t = threadIdx.x;          // 64 threads
  int b = t >> 4, h = t & 15;
  float s = bg[h];
  for (int i = 0; i < 64; i++) s += pf[b * 64 + i] * wg[i * NH + h];
  validity[t] = 1.0f / (1.0f + __expf(-s));
}

// ---------------- fp32 -> bf16 convert (8 elems/thread) ----------------
__global__ __launch_bounds__(256) void conv_bf16_kernel(const float* __restrict__ in,
                                                        unsigned short* __restrict__ out) {
  size_t i = ((size_t)blockIdx.x * 256 + threadIdx.x) * 8;
  float4 a = *(const float4*)(in + i);
  float4 b = *(const float4*)(in + i + 4);
  union { unsigned short us[8]; uint4 v; } o;
  o.us[0] = f2bf(a.x); o.us[1] = f2bf(a.y); o.us[2] = f2bf(a.z); o.us[3] = f2bf(a.w);
  o.us[4] = f2bf(b.x); o.us[5] = f2bf(b.y); o.us[6] = f2bf(b.z); o.us[7] = f2bf(b.w);
  *(uint4*)(out + i) = o.v;
}

// ---------------- W [K][N] fp32 -> Wt [N][K] bf16 (64x64 tiles) ----------------
__global__ __launch_bounds__(256) void wt_kernel(const float* __restrict__ W,
                                                 unsigned short* __restrict__ Wt) {
  __shared__ unsigned short T[64][72];
  int k0 = blockIdx.x * 64, n0 = blockIdx.y * 64;
  int t = threadIdx.x;
  int r = t >> 2, c4 = (t & 3) * 16;
  for (int j = 0; j < 16; j += 4) {
    float4 v = *(const float4*)&W[(size_t)(k0 + r) * DM + n0 + c4 + j];
    T[r][c4 + j + 0] = f2bf(v.x); T[r][c4 + j + 1] = f2bf(v.y);
    T[r][c4 + j + 2] = f2bf(v.z); T[r][c4 + j + 3] = f2bf(v.w);
  }
  __syncthreads();
  union { unsigned short us[16]; uint4 v[2]; } o;
  for (int j = 0; j < 16; j++) o.us[j] = T[c4 + j][r];
  *(uint4*)&Wt[(size_t)(n0 + r) * DM + k0 + c4] = o.v[0];
  *(uint4*)&Wt[(size_t)(n0 + r) * DM + k0 + c4 + 8] = o.v[1];
}

// ---------------- vh [BH][S][64] -> vhT [BH][64][S] (bf16) ----------------
__global__ __launch_bounds__(256) void vt_kernel(const unsigned short* __restrict__ vh,
                                                 unsigned short* __restrict__ vhT) {
  __shared__ unsigned short T[64][72];
  int bh = blockIdx.y;
  int s0 = blockIdx.x * 64;
  int t = threadIdx.x;
  int r = t >> 2, c4 = (t & 3) * 16;
  const unsigned short* src = vh + ((size_t)bh * S_LEN + s0 + r) * DEP + c4;
  *(uint4*)&T[r][c4] = *(const uint4*)src;
  *(uint4*)&T[r][c4 + 8] = *(const uint4*)(src + 8);
  __syncthreads();
  union { unsigned short us[16]; uint4 v[2]; } o;
  for (int j = 0; j < 16; j++) o.us[j] = T[c4 + j][r];
  unsigned short* dst = vhT + ((size_t)bh * DEP + r) * S_LEN + s0 + c4;
  *(uint4*)dst = o.v[0];
  *(uint4*)(dst + 8) = o.v[1];
}

// ---------------- projection GEMM: Y = X @ W + b, head-split bf16 output ----------------
__global__ __launch_bounds__(256) void proj_gemm(const unsigned short* __restrict__ A,
                                                 const unsigned short* __restrict__ Bt,
                                                 const float* __restrict__ bias,
                                                 unsigned short* __restrict__ Y) {
  __shared__ unsigned short As[128 * 64], Bs[128 * 64];
  const int K = DM;
  int tid = threadIdx.x, w = tid >> 6, l = tid & 63, g = l >> 4, lc = l & 15;
  int r0 = blockIdx.x * 128, c0 = blockIdx.y * 128;
  int wr = w >> 1, wc = w & 1;
  int lrow = l >> 3, lcol = (l & 7) * 8;
  f32x4 acc[4][4] = {};
  for (int k0 = 0; k0 < K; k0 += 64) {
    __syncthreads();
    for (int i = 0; i < 4; i++) {
      int row = (w * 4 + i) * 8 + lrow;
      gld16(A + (size_t)(r0 + row) * K + k0 + lcol, &As[(w * 4 + i) * 512]);
      gld16(Bt + (size_t)(c0 + row) * K + k0 + lcol, &Bs[(w * 4 + i) * 512]);
    }
    __syncthreads();
    for (int kk = 0; kk < 2; kk++) {
      short8 a[4], b[4];
      for (int m = 0; m < 4; m++)
        a[m] = *(const short8*)&As[(wr * 64 + m * 16 + lc) * 64 + kk * 32 + g * 8];
      for (int n = 0; n < 4; n++)
        b[n] = *(const short8*)&Bs[(wc * 64 + n * 16 + lc) * 64 + kk * 32 + g * 8];
      for (int m = 0; m < 4; m++)
        for (int n = 0; n < 4; n++)
          acc[m][n] = MFMA_BF16(a[m], b[n], acc[m][n]);
    }
  }
  for (int n = 0; n < 4; n++) {
    int c = c0 + wc * 64 + n * 16 + lc;
    float bi = bias[c];
    int h = c >> 6, d = c & 63;
    for (int m = 0; m < 4; m++) {
      int rowbase = r0 + wr * 64 + m * 16 + g * 4;
      for (int r = 0; r < 4; r++) {
        int row = rowbase + r;
        int b_ = row >> 11, s = row & 2047;
        Y[(((size_t)b_ * NH + h) * S_LEN + s) * DEP + d] = f2bf(acc[m][n][r] + bi);
      }
    }
  }
}

// ---------------- fused attention v3 ----------------
// 512 threads / 8 waves, Q-tile 128 rows. Pass 2: fp32 P tile in LDS per wave,
// vectorized non-temporal attn stores, cvt_pk bf16 fragments for PV.
__global__ __launch_bounds__(512, 4) void attn_fused(const unsigned short* __restrict__ qh,
                                                     const unsigned short* __restrict__ kh,
                                                     const unsigned short* __restrict__ vhT,
                                                     const float* __restrict__ validity,
                                                     const float* __restrict__ mask,
                                                     float* __restrict__ concat,
                                                     float* __restrict__ attn) {
  __shared__ union {
    unsigned short Q[128 * 64];      // 16 KB (pass 1)
    float PF[8][16 * 68];            // 34.8 KB (pass 2, per-wave [16 qrows][64 cols] pad 68)
  } QP;
  __shared__ unsigned short Ks[2][64 * 64], Vs[2][64 * 64];
  __shared__ float Ms[S_LEN];
  int bh = blockIdx.y, b = bh >> 4, h = bh & 15;
  int q0 = blockIdx.x * 128;
  int tid = threadIdx.x, w = tid >> 6, l = tid & 63, g = l >> 4, lc = l & 15;
  int srow = l >> 3;                 // staging row within wave chunk (0..7)
  int sgran = (l & 7) ^ srow;        // pre-swizzled global source granule
  float scale = validity[bh] * 0.125f * 1.44269504f;   // validity/sqrt(64)*log2(e)
  for (int i = tid; i < S_LEN; i += 512)
    Ms[i] = mask[(size_t)b * S_LEN + i] * (-1.44269504e9f);

  const unsigned short* qb = qh + (size_t)bh * S_LEN * DEP;
  const unsigned short* kb = kh + (size_t)bh * S_LEN * DEP;
  const unsigned short* vb = vhT + (size_t)bh * DEP * S_LEN;

  // stage Q (128 rows) and K tile 0, single barrier
  for (int i = 0; i < 2; i++)
    gld16(qb + (size_t)(q0 + i * 64 + w * 8 + srow) * DEP + sgran * 8,
          &QP.Q[(i * 64 + w * 8) * 64]);
  gld16(kb + (size_t)(w * 8 + srow) * DEP + sgran * 8, &Ks[0][w * 512]);
  __syncthreads();

  int qrow = w * 16 + lc;
  short8 aq0 = *(const short8*)&QP.Q[SWZ(qrow, g)];
  short8 aq1 = *(const short8*)&QP.Q[SWZ(qrow, 4 + g)];

  // ---- pass 1: row sums of exp ----
  float ell[4] = {0.f, 0.f, 0.f, 0.f};
  int buf = 0;
  for (int kt = 0; kt < 32; kt++) {
    if (kt < 31)
      gld16(kb + (size_t)((kt + 1) * 64 + w * 8 + srow) * DEP + sgran * 8,
            &Ks[buf ^ 1][w * 512]);
    for (int f = 0; f < 4; f++) {
      int krow = f * 16 + lc;
      short8 b0 = *(const short8*)&Ks[buf][SWZ(krow, g)];
      short8 b1 = *(const short8*)&Ks[buf][SWZ(krow, 4 + g)];
      f32x4 c = {};
      __builtin_amdgcn_s_setprio(1);
      c = MFMA_BF16(aq0, b0, c);
      c = MFMA_BF16(aq1, b1, c);
      __builtin_amdgcn_s_setprio(0);
      float mb = Ms[kt * 64 + f * 16 + lc];
      for (int r = 0; r < 4; r++) ell[r] += exp2f(fmaf(c[r], scale, mb));
    }
    __syncthreads();
    buf ^= 1;
  }
  for (int m = 8; m >= 1; m >>= 1)
    for (int r = 0; r < 4; r++) ell[r] += __shfl_xor(ell[r], m, 64);
  float rinv[4];
  for (int r = 0; r < 4; r++) rinv[r] = 1.0f / ell[r];

  // ---- pass 2 ----
  gld16(kb + (size_t)(w * 8 + srow) * DEP + sgran * 8, &Ks[0][w * 512]);
  gld16(vb + (size_t)(w * 8 + srow) * S_LEN + sgran * 8, &Vs[0][w * 512]);
  __syncthreads();

  float* PFw = QP.PF[w];
  int srowi = l & 15, sseg = l >> 4;   // store roles: 16 rows x 4 segs of 16 floats
  float* arow = attn + ((size_t)bh * S_LEN + q0 + w * 16 + srowi) * S_LEN + sseg * 16;
  const float* pfrow = &PFw[srowi * 68 + sseg * 16];

  f32x4 O[4] = {};
  buf = 0;
  for (int kt = 0; kt < 32; kt++) {
    if (kt < 31) {
      gld16(kb + (size_t)((kt + 1) * 64 + w * 8 + srow) * DEP + sgran * 8,
            &Ks[buf ^ 1][w * 512]);
      gld16(vb + (size_t)(w * 8 + srow) * S_LEN + (kt + 1) * 64 + sgran * 8,
            &Vs[buf ^ 1][w * 512]);
    }
    for (int f = 0; f < 4; f++) {
      int krow = f * 16 + lc;
      short8 b0 = *(const short8*)&Ks[buf][SWZ(krow, g)];
      short8 b1 = *(const short8*)&Ks[buf][SWZ(krow, 4 + g)];
      f32x4 c = {};
      __builtin_amdgcn_s_setprio(1);
      c = MFMA_BF16(aq0, b0, c);
      c = MFMA_BF16(aq1, b1, c);
      __builtin_amdgcn_s_setprio(0);
      float mb = Ms[kt * 64 + f * 16 + lc];
      for (int r = 0; r < 4; r++) {
        float p = exp2f(fmaf(c[r], scale, mb)) * rinv[r];
        PFw[(g * 4 + r) * 68 + f * 16 + lc] = p;
      }
    }
    // PV A-fragments from fp32 tile via cvt_pk (wave-private, no barrier)
    f32x4 t0 = *(const f32x4*)&PFw[lc * 68 + g * 8];
    f32x4 t1 = *(const f32x4*)&PFw[lc * 68 + g * 8 + 4];
    f32x4 t2 = *(const f32x4*)&PFw[lc * 68 + 32 + g * 8];
    f32x4 t3 = *(const f32x4*)&PFw[lc * 68 + 32 + g * 8 + 4];
    union { uint4 u; short8 s; } pk0, pk1;
    pk0.u = uint4{cvtpk(t0[0], t0[1]), cvtpk(t0[2], t0[3]),
                  cvtpk(t1[0], t1[1]), cvtpk(t1[2], t1[3])};
    pk1.u = uint4{cvtpk(t2[0], t2[1]), cvtpk(t2[2], t2[3]),
                  cvtpk(t3[0], t3[1]), cvtpk(t3[2], t3[3])};
    // vectorized non-temporal attn dump (16 floats/lane = full 16x64 tile/wave)
    for (int j = 0; j < 4; j++) {
      f32x4 tv = *(const f32x4*)(pfrow + j * 4);
      __builtin_nontemporal_store(tv, (f32x4*)(arow + kt * 64 + j * 4));
    }
    __builtin_amdgcn_s_setprio(1);
    for (int n = 0; n < 4; n++) {
      int vrow = n * 16 + lc;
      short8 v0 = *(const short8*)&Vs[buf][SWZ(vrow, g)];
      short8 v1 = *(const short8*)&Vs[buf][SWZ(vrow, 4 + g)];
      O[n] = MFMA_BF16(pk0.s, v0, O[n]);
      O[n] = MFMA_BF16(pk1.s, v1, O[n]);
    }
    __builtin_amdgcn_s_setprio(0);
    __syncthreads();
    buf ^= 1;
  }
  for (int n = 0; n < 4; n++)
    for (int r = 0; r < 4; r++)
      __builtin_nontemporal_store(
          O[n][r],
          concat + ((size_t)b * S_LEN + q0 + w * 16 + g * 4 + r) * DM + h * DEP + n * 16 + lc);
}

// ---------------- launch ----------------
extern "C" void kernel_launch(void* const* d_in, const int* in_sizes, int n_in,
                              void* d_out, int out_size, void* d_ws, size_t ws_size,
                              hipStream_t stream) {
  const float* q    = (const float*)d_in[0];
  const float* k    = (const float*)d_in[1];
  const float* v    = (const float*)d_in[2];
  const float* pf   = (const float*)d_in[3];
  const float* mask = (const float*)d_in[4];
  const float* wq   = (const float*)d_in[5];
  const float* bq   = (const float*)d_in[6];
  const float* wk   = (const float*)d_in[7];
  const float* bk   = (const float*)d_in[8];
  const float* wv   = (const float*)d_in[9];
  const float* bv   = (const float*)d_in[10];
  const float* wg   = (const float*)d_in[11];
  const float* bg   = (const float*)d_in[12];

  float* concat = (float*)d_out;
  float* attn   = concat + (size_t)NB * S_LEN * DM;   // 8388608 floats in

  // transient scratch inside the (not yet written) attn region of d_out:
  unsigned short* qbf = (unsigned short*)attn;     // 3 x 16.78 MB
  unsigned short* kbf = qbf + (size_t)MROWS * DM;
  unsigned short* vbf = kbf + (size_t)MROWS * DM;
  unsigned short* wqT = vbf + (size_t)MROWS * DM;  // 3 x 2 MB
  unsigned short* wkT = wqT + (size_t)DM * DM;
  unsigned short* wvT = wkT + (size_t)DM * DM;

  // persistent intermediates in d_ws (~67 MB):
  float* validity = (float*)d_ws;
  unsigned short* qhp = (unsigned short*)((char*)d_ws + 4096);
  unsigned short* khp = qhp + (size_t)MROWS * DM;
  unsigned short* vhp = khp + (size_t)MROWS * DM;
  unsigned short* vhT = vhp + (size_t)MROWS * DM;

  gate_kernel<<<1, 64, 0, stream>>>(pf, wg, bg, validity);

  conv_bf16_kernel<<<4096, 256, 0, stream>>>(q, qbf);
  conv_bf16_kernel<<<4096, 256, 0, stream>>>(k, kbf);
  conv_bf16_kernel<<<4096, 256, 0, stream>>>(v, vbf);

  wt_kernel<<<dim3(16, 16), 256, 0, stream>>>(wq, wqT);
  wt_kernel<<<dim3(16, 16), 256, 0, stream>>>(wk, wkT);
  wt_kernel<<<dim3(16, 16), 256, 0, stream>>>(wv, wvT);

  proj_gemm<<<dim3(64, 8), 256, 0, stream>>>(qbf, wqT, bq, qhp);
  proj_gemm<<<dim3(64, 8), 256, 0, stream>>>(kbf, wkT, bk, khp);
  proj_gemm<<<dim3(64, 8), 256, 0, stream>>>(vbf, wvT, bv, vhp);

  vt_kernel<<<dim3(32, 64), 256, 0, stream>>>(vhp, vhT);

  attn_fused<<<dim3(16, 64), 512, 0, stream>>>(qhp, khp, vhT, validity, mask, concat, attn);
}

// Round 4
// 630.050 us; speedup vs baseline: 3.3581x; 3.3581x over previous
//
#include <hip/hip_runtime.h>

// ---------------- constants ----------------
#define S_LEN 2048
#define NB 4
#define NH 16
#define BHN 64          // NB*NH
#define DM 1024
#define DEP 64
#define MROWS 8192      // NB*S_LEN

typedef __attribute__((ext_vector_type(8))) short short8;
typedef __attribute__((ext_vector_type(4))) float f32x4;

#define MFMA_BF16(a, b, c) __builtin_amdgcn_mfma_f32_16x16x32_bf16((a), (b), (c), 0, 0, 0)

typedef __attribute__((address_space(1))) const void* as1cv;
typedef __attribute__((address_space(3))) void* as3v;

__device__ __forceinline__ void gld16(const void* g, void* l) {
  // async global->LDS, 16B per lane; LDS dest = wave-uniform base + lane*16
  __builtin_amdgcn_global_load_lds((as1cv)g, (as3v)l, 16, 0, 0);
}

__device__ __forceinline__ unsigned short f2bf(float f) {
  unsigned u = __float_as_uint(f);
  u += 0x7fffu + ((u >> 16) & 1u);   // round-to-nearest-even
  return (unsigned short)(u >> 16);
}

// packed fp32x2 -> bf16x2 (RNE), 1 instruction; S0 -> low16, S1 -> high16
__device__ __forceinline__ unsigned cvtpk(float a, float b) {
  unsigned r;
  asm("v_cvt_pk_bf16_f32 %0, %1, %2" : "=v"(r) : "v"(a), "v"(b));
  return r;
}

// swizzled short-index of logical (row, 8-short granule) in a [rows][64] bf16 tile
__device__ __forceinline__ int SWZ(int row, int gran) {
  return row * 64 + ((gran ^ (row & 7)) << 3);
}

// ---------------- gate: validity[b][h] = sigmoid(pf @ wg + bg) ----------------
__global__ void gate_kernel(const float* __restrict__ pf, const float* __restrict__ wg,
                            const float* __restrict__ bg, float* __restrict__ validity) {
  int t = threadIdx.x;          // 64 threads
  int b = t >> 4, h = t & 15;
  float s = bg[h];
  for (int i = 0; i < 64; i++) s += pf[b * 64 + i] * wg[i * NH + h];
  validity[t] = 1.0f / (1.0f + __expf(-s));
}

// ---------------- fp32 -> bf16 convert (8 elems/thread) ----------------
__global__ __launch_bounds__(256) void conv_bf16_kernel(const float* __restrict__ in,
                                                        unsigned short* __restrict__ out) {
  size_t i = ((size_t)blockIdx.x * 256 + threadIdx.x) * 8;
  float4 a = *(const float4*)(in + i);
  float4 b = *(const float4*)(in + i + 4);
  union { unsigned short us[8]; uint4 v; } o;
  o.us[0] = f2bf(a.x); o.us[1] = f2bf(a.y); o.us[2] = f2bf(a.z); o.us[3] = f2bf(a.w);
  o.us[4] = f2bf(b.x); o.us[5] = f2bf(b.y); o.us[6] = f2bf(b.z); o.us[7] = f2bf(b.w);
  *(uint4*)(out + i) = o.v;
}

// ---------------- W [K][N] fp32 -> Wt [N][K] bf16 (64x64 tiles) ----------------
__global__ __launch_bounds__(256) void wt_kernel(const float* __restrict__ W,
                                                 unsigned short* __restrict__ Wt) {
  __shared__ unsigned short T[64][72];
  int k0 = blockIdx.x * 64, n0 = blockIdx.y * 64;
  int t = threadIdx.x;
  int r = t >> 2, c4 = (t & 3) * 16;
  for (int j = 0; j < 16; j += 4) {
    float4 v = *(const float4*)&W[(size_t)(k0 + r) * DM + n0 + c4 + j];
    T[r][c4 + j + 0] = f2bf(v.x); T[r][c4 + j + 1] = f2bf(v.y);
    T[r][c4 + j + 2] = f2bf(v.z); T[r][c4 + j + 3] = f2bf(v.w);
  }
  __syncthreads();
  union { unsigned short us[16]; uint4 v[2]; } o;
  for (int j = 0; j < 16; j++) o.us[j] = T[c4 + j][r];
  *(uint4*)&Wt[(size_t)(n0 + r) * DM + k0 + c4] = o.v[0];
  *(uint4*)&Wt[(size_t)(n0 + r) * DM + k0 + c4 + 8] = o.v[1];
}

// ---------------- vh [BH][S][64] -> vhT [BH][64][S] (bf16) ----------------
__global__ __launch_bounds__(256) void vt_kernel(const unsigned short* __restrict__ vh,
                                                 unsigned short* __restrict__ vhT) {
  __shared__ unsigned short T[64][72];
  int bh = blockIdx.y;
  int s0 = blockIdx.x * 64;
  int t = threadIdx.x;
  int r = t >> 2, c4 = (t & 3) * 16;
  const unsigned short* src = vh + ((size_t)bh * S_LEN + s0 + r) * DEP + c4;
  *(uint4*)&T[r][c4] = *(const uint4*)src;
  *(uint4*)&T[r][c4 + 8] = *(const uint4*)(src + 8);
  __syncthreads();
  union { unsigned short us[16]; uint4 v[2]; } o;
  for (int j = 0; j < 16; j++) o.us[j] = T[c4 + j][r];
  unsigned short* dst = vhT + ((size_t)bh * DEP + r) * S_LEN + s0 + c4;
  *(uint4*)dst = o.v[0];
  *(uint4*)(dst + 8) = o.v[1];
}

// ---------------- projection GEMM: Y = X @ W + b, head-split bf16 output ----------------
__global__ __launch_bounds__(256) void proj_gemm(const unsigned short* __restrict__ A,
                                                 const unsigned short* __restrict__ Bt,
                                                 const float* __restrict__ bias,
                                                 unsigned short* __restrict__ Y) {
  __shared__ unsigned short As[128 * 64], Bs[128 * 64];
  const int K = DM;
  int tid = threadIdx.x, w = tid >> 6, l = tid & 63, g = l >> 4, lc = l & 15;
  int r0 = blockIdx.x * 128, c0 = blockIdx.y * 128;
  int wr = w >> 1, wc = w & 1;
  int lrow = l >> 3, lcol = (l & 7) * 8;
  f32x4 acc[4][4] = {};
  for (int k0 = 0; k0 < K; k0 += 64) {
    __syncthreads();
    for (int i = 0; i < 4; i++) {
      int row = (w * 4 + i) * 8 + lrow;
      gld16(A + (size_t)(r0 + row) * K + k0 + lcol, &As[(w * 4 + i) * 512]);
      gld16(Bt + (size_t)(c0 + row) * K + k0 + lcol, &Bs[(w * 4 + i) * 512]);
    }
    __syncthreads();
    for (int kk = 0; kk < 2; kk++) {
      short8 a[4], b[4];
      for (int m = 0; m < 4; m++)
        a[m] = *(const short8*)&As[(wr * 64 + m * 16 + lc) * 64 + kk * 32 + g * 8];
      for (int n = 0; n < 4; n++)
        b[n] = *(const short8*)&Bs[(wc * 64 + n * 16 + lc) * 64 + kk * 32 + g * 8];
      for (int m = 0; m < 4; m++)
        for (int n = 0; n < 4; n++)
          acc[m][n] = MFMA_BF16(a[m], b[n], acc[m][n]);
    }
  }
  for (int n = 0; n < 4; n++) {
    int c = c0 + wc * 64 + n * 16 + lc;
    float bi = bias[c];
    int h = c >> 6, d = c & 63;
    for (int m = 0; m < 4; m++) {
      int rowbase = r0 + wr * 64 + m * 16 + g * 4;
      for (int r = 0; r < 4; r++) {
        int row = rowbase + r;
        int b_ = row >> 11, s = row & 2047;
        Y[(((size_t)b_ * NH + h) * S_LEN + s) * DEP + d] = f2bf(acc[m][n][r] + bi);
      }
    }
  }
}

// ---------------- fused attention v4 ----------------
// = v3 minus the two poisons: no forced occupancy bound, no non-temporal stores.
__global__ __launch_bounds__(512) void attn_fused(const unsigned short* __restrict__ qh,
                                                  const unsigned short* __restrict__ kh,
                                                  const unsigned short* __restrict__ vhT,
                                                  const float* __restrict__ validity,
                                                  const float* __restrict__ mask,
                                                  float* __restrict__ concat,
                                                  float* __restrict__ attn) {
  __shared__ union {
    unsigned short Q[128 * 64];      // 16 KB (pass 1)
    float PF[8][16 * 68];            // 34.8 KB (pass 2, per-wave [16 qrows][64 cols] pad 68)
  } QP;
  __shared__ unsigned short Ks[2][64 * 64], Vs[2][64 * 64];
  __shared__ float Ms[S_LEN];
  int bh = blockIdx.y, b = bh >> 4, h = bh & 15;
  int q0 = blockIdx.x * 128;
  int tid = threadIdx.x, w = tid >> 6, l = tid & 63, g = l >> 4, lc = l & 15;
  int srow = l >> 3;                 // staging row within wave chunk (0..7)
  int sgran = (l & 7) ^ srow;        // pre-swizzled global source granule
  float scale = validity[bh] * 0.125f * 1.44269504f;   // validity/sqrt(64)*log2(e)
  for (int i = tid; i < S_LEN; i += 512)
    Ms[i] = mask[(size_t)b * S_LEN + i] * (-1.44269504e9f);

  const unsigned short* qb = qh + (size_t)bh * S_LEN * DEP;
  const unsigned short* kb = kh + (size_t)bh * S_LEN * DEP;
  const unsigned short* vb = vhT + (size_t)bh * DEP * S_LEN;

  // stage Q (128 rows) and K tile 0, single barrier
  for (int i = 0; i < 2; i++)
    gld16(qb + (size_t)(q0 + i * 64 + w * 8 + srow) * DEP + sgran * 8,
          &QP.Q[(i * 64 + w * 8) * 64]);
  gld16(kb + (size_t)(w * 8 + srow) * DEP + sgran * 8, &Ks[0][w * 512]);
  __syncthreads();

  int qrow = w * 16 + lc;
  short8 aq0 = *(const short8*)&QP.Q[SWZ(qrow, g)];
  short8 aq1 = *(const short8*)&QP.Q[SWZ(qrow, 4 + g)];

  // ---- pass 1: row sums of exp ----
  float ell[4] = {0.f, 0.f, 0.f, 0.f};
  int buf = 0;
  for (int kt = 0; kt < 32; kt++) {
    if (kt < 31)
      gld16(kb + (size_t)((kt + 1) * 64 + w * 8 + srow) * DEP + sgran * 8,
            &Ks[buf ^ 1][w * 512]);
    for (int f = 0; f < 4; f++) {
      int krow = f * 16 + lc;
      short8 b0 = *(const short8*)&Ks[buf][SWZ(krow, g)];
      short8 b1 = *(const short8*)&Ks[buf][SWZ(krow, 4 + g)];
      f32x4 c = {};
      __builtin_amdgcn_s_setprio(1);
      c = MFMA_BF16(aq0, b0, c);
      c = MFMA_BF16(aq1, b1, c);
      __builtin_amdgcn_s_setprio(0);
      float mb = Ms[kt * 64 + f * 16 + lc];
      for (int r = 0; r < 4; r++) ell[r] += exp2f(fmaf(c[r], scale, mb));
    }
    __syncthreads();
    buf ^= 1;
  }
  for (int m = 8; m >= 1; m >>= 1)
    for (int r = 0; r < 4; r++) ell[r] += __shfl_xor(ell[r], m, 64);
  float rinv[4];
  for (int r = 0; r < 4; r++) rinv[r] = 1.0f / ell[r];

  // ---- pass 2 ----
  gld16(kb + (size_t)(w * 8 + srow) * DEP + sgran * 8, &Ks[0][w * 512]);
  gld16(vb + (size_t)(w * 8 + srow) * S_LEN + sgran * 8, &Vs[0][w * 512]);
  __syncthreads();

  float* PFw = QP.PF[w];
  int srowi = l & 15, sseg = l >> 4;   // store roles: 16 rows x 4 segs of 16 floats
  float* arow = attn + ((size_t)bh * S_LEN + q0 + w * 16 + srowi) * S_LEN + sseg * 16;
  const float* pfrow = &PFw[srowi * 68 + sseg * 16];

  f32x4 O[4] = {};
  buf = 0;
  for (int kt = 0; kt < 32; kt++) {
    if (kt < 31) {
      gld16(kb + (size_t)((kt + 1) * 64 + w * 8 + srow) * DEP + sgran * 8,
            &Ks[buf ^ 1][w * 512]);
      gld16(vb + (size_t)(w * 8 + srow) * S_LEN + (kt + 1) * 64 + sgran * 8,
            &Vs[buf ^ 1][w * 512]);
    }
    for (int f = 0; f < 4; f++) {
      int krow = f * 16 + lc;
      short8 b0 = *(const short8*)&Ks[buf][SWZ(krow, g)];
      short8 b1 = *(const short8*)&Ks[buf][SWZ(krow, 4 + g)];
      f32x4 c = {};
      __builtin_amdgcn_s_setprio(1);
      c = MFMA_BF16(aq0, b0, c);
      c = MFMA_BF16(aq1, b1, c);
      __builtin_amdgcn_s_setprio(0);
      float mb = Ms[kt * 64 + f * 16 + lc];
      for (int r = 0; r < 4; r++) {
        float p = exp2f(fmaf(c[r], scale, mb)) * rinv[r];
        PFw[(g * 4 + r) * 68 + f * 16 + lc] = p;
      }
    }
    // PV A-fragments from fp32 tile via cvt_pk (wave-private, no barrier)
    f32x4 t0 = *(const f32x4*)&PFw[lc * 68 + g * 8];
    f32x4 t1 = *(const f32x4*)&PFw[lc * 68 + g * 8 + 4];
    f32x4 t2 = *(const f32x4*)&PFw[lc * 68 + 32 + g * 8];
    f32x4 t3 = *(const f32x4*)&PFw[lc * 68 + 32 + g * 8 + 4];
    union { uint4 u; short8 s; } pk0, pk1;
    pk0.u = uint4{cvtpk(t0[0], t0[1]), cvtpk(t0[2], t0[3]),
                  cvtpk(t1[0], t1[1]), cvtpk(t1[2], t1[3])};
    pk1.u = uint4{cvtpk(t2[0], t2[1]), cvtpk(t2[2], t2[3]),
                  cvtpk(t3[0], t3[1]), cvtpk(t3[2], t3[3])};
    // vectorized attn dump (16 floats/lane = full 16x64 tile/wave), cached stores
    for (int j = 0; j < 4; j++) {
      f32x4 tv = *(const f32x4*)(pfrow + j * 4);
      *(f32x4*)(arow + kt * 64 + j * 4) = tv;
    }
    __builtin_amdgcn_s_setprio(1);
    for (int n = 0; n < 4; n++) {
      int vrow = n * 16 + lc;
      short8 v0 = *(const short8*)&Vs[buf][SWZ(vrow, g)];
      short8 v1 = *(const short8*)&Vs[buf][SWZ(vrow, 4 + g)];
      O[n] = MFMA_BF16(pk0.s, v0, O[n]);
      O[n] = MFMA_BF16(pk1.s, v1, O[n]);
    }
    __builtin_amdgcn_s_setprio(0);
    __syncthreads();
    buf ^= 1;
  }
  for (int n = 0; n < 4; n++)
    for (int r = 0; r < 4; r++)
      concat[((size_t)b * S_LEN + q0 + w * 16 + g * 4 + r) * DM + h * DEP + n * 16 + lc] =
          O[n][r];
}

// ---------------- launch ----------------
extern "C" void kernel_launch(void* const* d_in, const int* in_sizes, int n_in,
                              void* d_out, int out_size, void* d_ws, size_t ws_size,
                              hipStream_t stream) {
  const float* q    = (const float*)d_in[0];
  const float* k    = (const float*)d_in[1];
  const float* v    = (const float*)d_in[2];
  const float* pf   = (const float*)d_in[3];
  const float* mask = (const float*)d_in[4];
  const float* wq   = (const float*)d_in[5];
  const float* bq   = (const float*)d_in[6];
  const float* wk   = (const float*)d_in[7];
  const float* bk   = (const float*)d_in[8];
  const float* wv   = (const float*)d_in[9];
  const float* bv   = (const float*)d_in[10];
  const float* wg   = (const float*)d_in[11];
  const float* bg   = (const float*)d_in[12];

  float* concat = (float*)d_out;
  float* attn   = concat + (size_t)NB * S_LEN * DM;   // 8388608 floats in

  // transient scratch inside the (not yet written) attn region of d_out:
  unsigned short* qbf = (unsigned short*)attn;     // 3 x 16.78 MB
  unsigned short* kbf = qbf + (size_t)MROWS * DM;
  unsigned short* vbf = kbf + (size_t)MROWS * DM;
  unsigned short* wqT = vbf + (size_t)MROWS * DM;  // 3 x 2 MB
  unsigned short* wkT = wqT + (size_t)DM * DM;
  unsigned short* wvT = wkT + (size_t)DM * DM;

  // persistent intermediates in d_ws (~67 MB):
  float* validity = (float*)d_ws;
  unsigned short* qhp = (unsigned short*)((char*)d_ws + 4096);
  unsigned short* khp = qhp + (size_t)MROWS * DM;
  unsigned short* vhp = khp + (size_t)MROWS * DM;
  unsigned short* vhT = vhp + (size_t)MROWS * DM;

  gate_kernel<<<1, 64, 0, stream>>>(pf, wg, bg, validity);

  conv_bf16_kernel<<<4096, 256, 0, stream>>>(q, qbf);
  conv_bf16_kernel<<<4096, 256, 0, stream>>>(k, kbf);
  conv_bf16_kernel<<<4096, 256, 0, stream>>>(v, vbf);

  wt_kernel<<<dim3(16, 16), 256, 0, stream>>>(wq, wqT);
  wt_kernel<<<dim3(16, 16), 256, 0, stream>>>(wk, wkT);
  wt_kernel<<<dim3(16, 16), 256, 0, stream>>>(wv, wvT);

  proj_gemm<<<dim3(64, 8), 256, 0, stream>>>(qbf, wqT, bq, qhp);
  proj_gemm<<<dim3(64, 8), 256, 0, stream>>>(kbf, wkT, bk, khp);
  proj_gemm<<<dim3(64, 8), 256, 0, stream>>>(vbf, wvT, bv, vhp);

  vt_kernel<<<dim3(32, 64), 256, 0, stream>>>(vhp, vhT);

  attn_fused<<<dim3(16, 64), 512, 0, stream>>>(qhp, khp, vhT, validity, mask, concat, attn);
}

// Round 5
// 536.802 us; speedup vs baseline: 3.9415x; 1.1737x over previous
//
#include <hip/hip_runtime.h>

// ---------------- constants ----------------
#define S_LEN 2048
#define NB 4
#define NH 16
#define BHN 64          // NB*NH
#define DM 1024
#define DEP 64
#define MROWS 8192      // NB*S_LEN

typedef __attribute__((ext_vector_type(8))) short short8;
typedef __attribute__((ext_vector_type(4))) float f32x4;

#define MFMA_BF16(a, b, c) __builtin_amdgcn_mfma_f32_16x16x32_bf16((a), (b), (c), 0, 0, 0)

typedef __attribute__((address_space(1))) const void* as1cv;
typedef __attribute__((address_space(3))) void* as3v;

__device__ __forceinline__ void gld16(const void* g, void* l) {
  // async global->LDS, 16B per lane; LDS dest = wave-uniform base + lane*16
  __builtin_amdgcn_global_load_lds((as1cv)g, (as3v)l, 16, 0, 0);
}

__device__ __forceinline__ unsigned short f2bf(float f) {
  unsigned u = __float_as_uint(f);
  u += 0x7fffu + ((u >> 16) & 1u);   // round-to-nearest-even
  return (unsigned short)(u >> 16);
}

// packed fp32x2 -> bf16x2 (RNE), 1 instruction; S0 -> low16, S1 -> high16
__device__ __forceinline__ unsigned cvtpk(float a, float b) {
  unsigned r;
  asm("v_cvt_pk_bf16_f32 %0, %1, %2" : "=v"(r) : "v"(a), "v"(b));
  return r;
}

// swizzled short-index of logical (row, 8-short granule) in a [rows][64] bf16 tile
__device__ __forceinline__ int SWZ(int row, int gran) {
  return row * 64 + ((gran ^ (row & 7)) << 3);
}

// ---------------- gate: validity[b][h] = sigmoid(pf @ wg + bg) ----------------
__global__ void gate_kernel(const float* __restrict__ pf, const float* __restrict__ wg,
                            const float* __restrict__ bg, float* __restrict__ validity) {
  int t = threadIdx.x;          // 64 threads
  int b = t >> 4, h = t & 15;
  float s = bg[h];
  for (int i = 0; i < 64; i++) s += pf[b * 64 + i] * wg[i * NH + h];
  validity[t] = 1.0f / (1.0f + __expf(-s));
}

// ---------------- fp32 -> bf16 convert (8 elems/thread) ----------------
__global__ __launch_bounds__(256) void conv_bf16_kernel(const float* __restrict__ in,
                                                        unsigned short* __restrict__ out) {
  size_t i = ((size_t)blockIdx.x * 256 + threadIdx.x) * 8;
  float4 a = *(const float4*)(in + i);
  float4 b = *(const float4*)(in + i + 4);
  union { unsigned short us[8]; uint4 v; } o;
  o.us[0] = f2bf(a.x); o.us[1] = f2bf(a.y); o.us[2] = f2bf(a.z); o.us[3] = f2bf(a.w);
  o.us[4] = f2bf(b.x); o.us[5] = f2bf(b.y); o.us[6] = f2bf(b.z); o.us[7] = f2bf(b.w);
  *(uint4*)(out + i) = o.v;
}

// ---------------- W [K][N] fp32 -> Wt [N][K] bf16 (64x64 tiles) ----------------
__global__ __launch_bounds__(256) void wt_kernel(const float* __restrict__ W,
                                                 unsigned short* __restrict__ Wt) {
  __shared__ unsigned short T[64][72];
  int k0 = blockIdx.x * 64, n0 = blockIdx.y * 64;
  int t = threadIdx.x;
  int r = t >> 2, c4 = (t & 3) * 16;
  for (int j = 0; j < 16; j += 4) {
    float4 v = *(const float4*)&W[(size_t)(k0 + r) * DM + n0 + c4 + j];
    T[r][c4 + j + 0] = f2bf(v.x); T[r][c4 + j + 1] = f2bf(v.y);
    T[r][c4 + j + 2] = f2bf(v.z); T[r][c4 + j + 3] = f2bf(v.w);
  }
  __syncthreads();
  union { unsigned short us[16]; uint4 v[2]; } o;
  for (int j = 0; j < 16; j++) o.us[j] = T[c4 + j][r];
  *(uint4*)&Wt[(size_t)(n0 + r) * DM + k0 + c4] = o.v[0];
  *(uint4*)&Wt[(size_t)(n0 + r) * DM + k0 + c4 + 8] = o.v[1];
}

// ---------------- vh [BH][S][64] -> vhT [BH][64][S] (bf16) ----------------
__global__ __launch_bounds__(256) void vt_kernel(const unsigned short* __restrict__ vh,
                                                 unsigned short* __restrict__ vhT) {
  __shared__ unsigned short T[64][72];
  int bh = blockIdx.y;
  int s0 = blockIdx.x * 64;
  int t = threadIdx.x;
  int r = t >> 2, c4 = (t & 3) * 16;
  const unsigned short* src = vh + ((size_t)bh * S_LEN + s0 + r) * DEP + c4;
  *(uint4*)&T[r][c4] = *(const uint4*)src;
  *(uint4*)&T[r][c4 + 8] = *(const uint4*)(src + 8);
  __syncthreads();
  union { unsigned short us[16]; uint4 v[2]; } o;
  for (int j = 0; j < 16; j++) o.us[j] = T[c4 + j][r];
  unsigned short* dst = vhT + ((size_t)bh * DEP + r) * S_LEN + s0 + c4;
  *(uint4*)dst = o.v[0];
  *(uint4*)(dst + 8) = o.v[1];
}

// ---------------- projection GEMM: Y = X @ W + b, head-split bf16 output ----------------
__global__ __launch_bounds__(256) void proj_gemm(const unsigned short* __restrict__ A,
                                                 const unsigned short* __restrict__ Bt,
                                                 const float* __restrict__ bias,
                                                 unsigned short* __restrict__ Y) {
  __shared__ unsigned short As[128 * 64], Bs[128 * 64];
  const int K = DM;
  int tid = threadIdx.x, w = tid >> 6, l = tid & 63, g = l >> 4, lc = l & 15;
  int r0 = blockIdx.x * 128, c0 = blockIdx.y * 128;
  int wr = w >> 1, wc = w & 1;
  int lrow = l >> 3, lcol = (l & 7) * 8;
  f32x4 acc[4][4] = {};
  for (int k0 = 0; k0 < K; k0 += 64) {
    __syncthreads();
    for (int i = 0; i < 4; i++) {
      int row = (w * 4 + i) * 8 + lrow;
      gld16(A + (size_t)(r0 + row) * K + k0 + lcol, &As[(w * 4 + i) * 512]);
      gld16(Bt + (size_t)(c0 + row) * K + k0 + lcol, &Bs[(w * 4 + i) * 512]);
    }
    __syncthreads();
    for (int kk = 0; kk < 2; kk++) {
      short8 a[4], b[4];
      for (int m = 0; m < 4; m++)
        a[m] = *(const short8*)&As[(wr * 64 + m * 16 + lc) * 64 + kk * 32 + g * 8];
      for (int n = 0; n < 4; n++)
        b[n] = *(const short8*)&Bs[(wc * 64 + n * 16 + lc) * 64 + kk * 32 + g * 8];
      for (int m = 0; m < 4; m++)
        for (int n = 0; n < 4; n++)
          acc[m][n] = MFMA_BF16(a[m], b[n], acc[m][n]);
    }
  }
  for (int n = 0; n < 4; n++) {
    int c = c0 + wc * 64 + n * 16 + lc;
    float bi = bias[c];
    int h = c >> 6, d = c & 63;
    for (int m = 0; m < 4; m++) {
      int rowbase = r0 + wr * 64 + m * 16 + g * 4;
      for (int r = 0; r < 4; r++) {
        int row = rowbase + r;
        int b_ = row >> 11, s = row & 2047;
        Y[(((size_t)b_ * NH + h) * S_LEN + s) * DEP + d] = f2bf(acc[m][n][r] + bi);
      }
    }
  }
}

// ---------------- fused attention v5 ----------------
// v4 + T4 counted-vmcnt: raw s_barrier per kt, prefetch/store-acks stay in flight.
__global__ __launch_bounds__(512) void attn_fused(const unsigned short* __restrict__ qh,
                                                  const unsigned short* __restrict__ kh,
                                                  const unsigned short* __restrict__ vhT,
                                                  const float* __restrict__ validity,
                                                  const float* __restrict__ mask,
                                                  float* __restrict__ concat,
                                                  float* __restrict__ attn) {
  __shared__ union {
    unsigned short Q[128 * 64];      // 16 KB (pass 1)
    float PF[8][16 * 68];            // 34.8 KB (pass 2, per-wave [16 qrows][64 cols] pad 68)
  } QP;
  __shared__ unsigned short Ks[2][64 * 64], Vs[2][64 * 64];
  __shared__ float Ms[S_LEN];
  int bh = blockIdx.y, b = bh >> 4, h = bh & 15;
  int q0 = blockIdx.x * 128;
  int tid = threadIdx.x, w = tid >> 6, l = tid & 63, g = l >> 4, lc = l & 15;
  int srow = l >> 3;                 // staging row within wave chunk (0..7)
  int sgran = (l & 7) ^ srow;        // pre-swizzled global source granule
  float scale = validity[bh] * 0.125f * 1.44269504f;   // validity/sqrt(64)*log2(e)
  for (int i = tid; i < S_LEN; i += 512)
    Ms[i] = mask[(size_t)b * S_LEN + i] * (-1.44269504e9f);

  const unsigned short* qb = qh + (size_t)bh * S_LEN * DEP;
  const unsigned short* kb = kh + (size_t)bh * S_LEN * DEP;
  const unsigned short* vb = vhT + (size_t)bh * DEP * S_LEN;

  // stage Q (128 rows) and K tile 0; full drain once
  for (int i = 0; i < 2; i++)
    gld16(qb + (size_t)(q0 + i * 64 + w * 8 + srow) * DEP + sgran * 8,
          &QP.Q[(i * 64 + w * 8) * 64]);
  gld16(kb + (size_t)(w * 8 + srow) * DEP + sgran * 8, &Ks[0][w * 512]);
  __syncthreads();

  int qrow = w * 16 + lc;
  short8 aq0 = *(const short8*)&QP.Q[SWZ(qrow, g)];
  short8 aq1 = *(const short8*)&QP.Q[SWZ(qrow, 4 + g)];

  // ---- pass 1: row sums of exp (1 load/iter/wave -> vmcnt(1)) ----
  float ell[4] = {0.f, 0.f, 0.f, 0.f};
#pragma unroll 2
  for (int kt = 0; kt < 32; kt++) {
    const int cb = kt & 1;
    if (kt < 31)
      gld16(kb + (size_t)((kt + 1) * 64 + w * 8 + srow) * DEP + sgran * 8,
            &Ks[cb ^ 1][w * 512]);
    __builtin_amdgcn_sched_barrier(0);
    if (kt < 31) { asm volatile("s_waitcnt vmcnt(1)" ::: "memory"); }
    else         { asm volatile("s_waitcnt vmcnt(0)" ::: "memory"); }
    __builtin_amdgcn_sched_barrier(0);
    for (int f = 0; f < 4; f++) {
      int krow = f * 16 + lc;
      short8 b0 = *(const short8*)&Ks[cb][SWZ(krow, g)];
      short8 b1 = *(const short8*)&Ks[cb][SWZ(krow, 4 + g)];
      f32x4 c = {};
      __builtin_amdgcn_s_setprio(1);
      c = MFMA_BF16(aq0, b0, c);
      c = MFMA_BF16(aq1, b1, c);
      __builtin_amdgcn_s_setprio(0);
      float mb = Ms[kt * 64 + f * 16 + lc];
      for (int r = 0; r < 4; r++) ell[r] += exp2f(fmaf(c[r], scale, mb));
    }
    __builtin_amdgcn_s_barrier();
  }
  for (int m = 8; m >= 1; m >>= 1)
    for (int r = 0; r < 4; r++) ell[r] += __shfl_xor(ell[r], m, 64);
  float rinv[4];
  for (int r = 0; r < 4; r++) rinv[r] = 1.0f / ell[r];

  // ---- pass 2 (2 loads + 4 stores/iter/wave -> vmcnt(6), tail vmcnt(4)) ----
  gld16(kb + (size_t)(w * 8 + srow) * DEP + sgran * 8, &Ks[0][w * 512]);
  gld16(vb + (size_t)(w * 8 + srow) * S_LEN + sgran * 8, &Vs[0][w * 512]);
  __syncthreads();

  float* PFw = QP.PF[w];
  // direct attn store base: this lane owns q-row (w*16+lc), col granule g*8 (+0/+32)
  float* arow2 = attn + ((size_t)bh * S_LEN + q0 + w * 16 + lc) * S_LEN + g * 8;

  f32x4 O[4] = {};
#pragma unroll 2
  for (int kt = 0; kt < 32; kt++) {
    const int cb = kt & 1;
    if (kt < 31) {
      gld16(kb + (size_t)((kt + 1) * 64 + w * 8 + srow) * DEP + sgran * 8,
            &Ks[cb ^ 1][w * 512]);
      gld16(vb + (size_t)(w * 8 + srow) * S_LEN + (kt + 1) * 64 + sgran * 8,
            &Vs[cb ^ 1][w * 512]);
    }
    __builtin_amdgcn_sched_barrier(0);
    if (kt < 31) { asm volatile("s_waitcnt vmcnt(6)" ::: "memory"); }
    else         { asm volatile("s_waitcnt vmcnt(4)" ::: "memory"); }
    __builtin_amdgcn_sched_barrier(0);
    for (int f = 0; f < 4; f++) {
      int krow = f * 16 + lc;
      short8 b0 = *(const short8*)&Ks[cb][SWZ(krow, g)];
      short8 b1 = *(const short8*)&Ks[cb][SWZ(krow, 4 + g)];
      f32x4 c = {};
      __builtin_amdgcn_s_setprio(1);
      c = MFMA_BF16(aq0, b0, c);
      c = MFMA_BF16(aq1, b1, c);
      __builtin_amdgcn_s_setprio(0);
      float mb = Ms[kt * 64 + f * 16 + lc];
      for (int r = 0; r < 4; r++) {
        float p = exp2f(fmaf(c[r], scale, mb)) * rinv[r];
        PFw[(g * 4 + r) * 68 + f * 16 + lc] = p;
      }
    }
    // transposed read of this wave's P tile: row lc, cols g*8.. / 32+g*8..
    f32x4 t0 = *(const f32x4*)&PFw[lc * 68 + g * 8];
    f32x4 t1 = *(const f32x4*)&PFw[lc * 68 + g * 8 + 4];
    f32x4 t2 = *(const f32x4*)&PFw[lc * 68 + 32 + g * 8];
    f32x4 t3 = *(const f32x4*)&PFw[lc * 68 + 32 + g * 8 + 4];
    union { uint4 u; short8 s; } pk0, pk1;
    pk0.u = uint4{cvtpk(t0[0], t0[1]), cvtpk(t0[2], t0[3]),
                  cvtpk(t1[0], t1[1]), cvtpk(t1[2], t1[3])};
    pk1.u = uint4{cvtpk(t2[0], t2[1]), cvtpk(t2[2], t2[3]),
                  cvtpk(t3[0], t3[1]), cvtpk(t3[2], t3[3])};
    // attn dump straight from the transposed regs (4 dwordx4/lane, cached)
    *(f32x4*)(arow2 + kt * 64) = t0;
    *(f32x4*)(arow2 + kt * 64 + 4) = t1;
    *(f32x4*)(arow2 + kt * 64 + 32) = t2;
    *(f32x4*)(arow2 + kt * 64 + 36) = t3;
    __builtin_amdgcn_s_setprio(1);
    for (int n = 0; n < 4; n++) {
      int vrow = n * 16 + lc;
      short8 v0 = *(const short8*)&Vs[cb][SWZ(vrow, g)];
      short8 v1 = *(const short8*)&Vs[cb][SWZ(vrow, 4 + g)];
      O[n] = MFMA_BF16(pk0.s, v0, O[n]);
      O[n] = MFMA_BF16(pk1.s, v1, O[n]);
    }
    __builtin_amdgcn_s_setprio(0);
    __builtin_amdgcn_s_barrier();
  }
  for (int n = 0; n < 4; n++)
    for (int r = 0; r < 4; r++)
      concat[((size_t)b * S_LEN + q0 + w * 16 + g * 4 + r) * DM + h * DEP + n * 16 + lc] =
          O[n][r];
}

// ---------------- launch ----------------
extern "C" void kernel_launch(void* const* d_in, const int* in_sizes, int n_in,
                              void* d_out, int out_size, void* d_ws, size_t ws_size,
                              hipStream_t stream) {
  const float* q    = (const float*)d_in[0];
  const float* k    = (const float*)d_in[1];
  const float* v    = (const float*)d_in[2];
  const float* pf   = (const float*)d_in[3];
  const float* mask = (const float*)d_in[4];
  const float* wq   = (const float*)d_in[5];
  const float* bq   = (const float*)d_in[6];
  const float* wk   = (const float*)d_in[7];
  const float* bk   = (const float*)d_in[8];
  const float* wv   = (const float*)d_in[9];
  const float* bv   = (const float*)d_in[10];
  const float* wg   = (const float*)d_in[11];
  const float* bg   = (const float*)d_in[12];

  float* concat = (float*)d_out;
  float* attn   = concat + (size_t)NB * S_LEN * DM;   // 8388608 floats in

  // transient scratch inside the (not yet written) attn region of d_out:
  unsigned short* qbf = (unsigned short*)attn;     // 3 x 16.78 MB
  unsigned short* kbf = qbf + (size_t)MROWS * DM;
  unsigned short* vbf = kbf + (size_t)MROWS * DM;
  unsigned short* wqT = vbf + (size_t)MROWS * DM;  // 3 x 2 MB
  unsigned short* wkT = wqT + (size_t)DM * DM;
  unsigned short* wvT = wkT + (size_t)DM * DM;

  // persistent intermediates in d_ws (~67 MB):
  float* validity = (float*)d_ws;
  unsigned short* qhp = (unsigned short*)((char*)d_ws + 4096);
  unsigned short* khp = qhp + (size_t)MROWS * DM;
  unsigned short* vhp = khp + (size_t)MROWS * DM;
  unsigned short* vhT = vhp + (size_t)MROWS * DM;

  gate_kernel<<<1, 64, 0, stream>>>(pf, wg, bg, validity);

  conv_bf16_kernel<<<4096, 256, 0, stream>>>(q, qbf);
  conv_bf16_kernel<<<4096, 256, 0, stream>>>(k, kbf);
  conv_bf16_kernel<<<4096, 256, 0, stream>>>(v, vbf);

  wt_kernel<<<dim3(16, 16), 256, 0, stream>>>(wq, wqT);
  wt_kernel<<<dim3(16, 16), 256, 0, stream>>>(wk, wkT);
  wt_kernel<<<dim3(16, 16), 256, 0, stream>>>(wv, wvT);

  proj_gemm<<<dim3(64, 8), 256, 0, stream>>>(qbf, wqT, bq, qhp);
  proj_gemm<<<dim3(64, 8), 256, 0, stream>>>(kbf, wkT, bk, khp);
  proj_gemm<<<dim3(64, 8), 256, 0, stream>>>(vbf, wvT, bv, vhp);

  vt_kernel<<<dim3(32, 64), 256, 0, stream>>>(vhp, vhT);

  attn_fused<<<dim3(16, 64), 512, 0, stream>>>(qhp, khp, vhT, validity, mask, concat, attn);
}